// Round 5
// baseline (197.543 us; speedup 1.0000x reference)
//
#include <hip/hip_runtime.h>
#include <hip/hip_bf16.h>

// TreeMLP fused kernel for MI355X (gfx950), round 14 — single-delta bisect.
//
// R14 = R0/R10 VERBATIM (k_treemlp, k_reduce, k_init_out all proven at
// 195us) + ONLY k_prep's w1/w2 branches rewritten (coalesced float4 tile ->
// LDS -> frag emit; was 8 scalar fp32 loads at 16KB stride per thread).
// R11/R12/R13 all failed with absmax == max|ref| (out==0 exactly: any bug
// zeroing xt/w1t/w2t gives out==0 since b1=b2=0 and gelu(0)=0). This round
// isolates k_prep; k_reduce stays R10-scalar.
//
// ws layout (same as R10):
//   xt : fp16 [128 tg][64 kf][64 lane][8]      8 MB   (32x32 B-frag order)
//   w1t: fp16 [8 hq][64 kf][16 ht][64 lane][8] 8 MB   (32x32 A-frag order)
//   w2t: fp16 [8 hq][32 kf][4 rt][64 lane][8]  1 MB   (32x32 B-frag order)
//   partial: u32 [8 hq][64 tt][8 j][32 tc][128 r]     64 MB
// total 84,934,656 B.

typedef _Float16 half8 __attribute__((ext_vector_type(8)));
typedef _Float16 half4 __attribute__((ext_vector_type(4)));
typedef _Float16 half2v __attribute__((ext_vector_type(2)));
typedef __fp16   fp16x2 __attribute__((ext_vector_type(2)));
typedef float    f32x4  __attribute__((ext_vector_type(4)));
typedef float    f32x16 __attribute__((ext_vector_type(16)));

#define MFMA3216(A,B,C) __builtin_amdgcn_mfma_f32_32x32x16_f16(A, B, C, 0, 0, 0)

__device__ __forceinline__ float gelu_f(float x){
  // 0.5x(1+tanh(c(x+0.044715x^3))) == x * sigmoid(x*(2c + 2c*0.044715*x^2))
  // folded with log2(e) for direct exp2
  float t2 = x * fmaf(x*x, -0.10294324f, -2.30220842f);
  float e  = __builtin_amdgcn_exp2f(t2);
  return x * __builtin_amdgcn_rcpf(1.0f + e);
}

#define XROW 1028   // x-prep LDS row stride in halves (1024 + 4: 2-way free)
#define W1ROW 258   // w1-prep LDS row stride in halves
#define W2ROW 130   // w2-prep LDS row stride in halves

// ---- fused prep: cast fp32->fp16 into MFMA fragment lane order ----
// grid 1408: [0,128) x-branch, [128,1152) w1-branch, [1152,1408) w2-branch.
__global__ void k_prep(const float* __restrict__ x, const float* __restrict__ w1,
                       const float* __restrict__ w2,
                       _Float16* __restrict__ xt, _Float16* __restrict__ w1t,
                       _Float16* __restrict__ w2t){
  __shared__ _Float16 Xs[32*XROW];                   // 65.8 KB (x-branch only)
  int bid = blockIdx.x;
  int t   = threadIdx.x;
  if (bid < 128){                                    // xt: 32x32 B-frags
    // phase 1: coalesced read of 32 tokens x 1024 cols -> padded LDS
    const float4* x4 = reinterpret_cast<const float4*>(x) + (size_t)bid*8192;
    #pragma unroll
    for (int i = 0; i < 32; ++i){
      float4 v = x4[i*256 + t];
      half4 h;
      h[0]=(_Float16)v.x; h[1]=(_Float16)v.y; h[2]=(_Float16)v.z; h[3]=(_Float16)v.w;
      *reinterpret_cast<half4*>(Xs + i*XROW + t*4) = h;
    }
    __syncthreads();
    // phase 2: emit 32x32 B-fragments (tg = bid)
    #pragma unroll
    for (int f = 0; f < 16; ++f){
      int fragidx = f*256 + t;                       // [kf 64][lane 64]
      int lane = fragidx & 63, kf = fragidx >> 6;
      int tok32 = lane & 31;
      int k = kf*16 + (lane >> 5)*8;
      half8 v = *reinterpret_cast<const half8*>(Xs + tok32*XROW + k);
      *reinterpret_cast<half8*>(xt + ((size_t)bid*4096 + fragidx)*8) = v;
    }
  } else if (bid < 1152){                            // w1t: 32x32 A-frags
    // block = (kf, ng): k-rows [kf*16,+16), n-cols [ng*256,+256)
    int bid2 = bid - 128;
    int kf = bid2 >> 4, ng = bid2 & 15;
    _Float16* Ws = Xs;                               // reuse, [16][W1ROW]
    // phase 1: coalesced load 16 x 256 floats (w1 row = 1024 float4s)
    const float4* w1f4 = reinterpret_cast<const float4*>(w1);
    #pragma unroll
    for (int q = 0; q < 4; ++q){
      int idx = q*256 + t;
      int row = idx >> 6, col4 = idx & 63;
      float4 v = w1f4[(size_t)(kf*16 + row)*1024 + ng*64 + col4];
      half4 h;
      h[0]=(_Float16)v.x; h[1]=(_Float16)v.y; h[2]=(_Float16)v.z; h[3]=(_Float16)v.w;
      *reinterpret_cast<half4*>(Ws + row*W1ROW + col4*4) = h;
    }
    __syncthreads();
    // phase 2: emit frags. hq = ng>>1, ht = (ng&1)*8 + htl
    int hq = ng >> 1;
    #pragma unroll
    for (int e = 0; e < 2; ++e){
      int fl = e*256 + t;                            // 512 frag-lanes
      int lane = fl & 63, htl = fl >> 6;
      int ht = (ng & 1)*8 + htl;
      int r0 = (lane >> 5)*8, c = htl*32 + (lane & 31);
      half8 v;
      #pragma unroll
      for (int j = 0; j < 8; ++j) v[j] = Ws[(r0 + j)*W1ROW + c];
      *reinterpret_cast<half8*>(
          w1t + ((size_t)hq*65536 + (size_t)kf*1024 + ht*64 + lane)*8) = v;
    }
  } else {                                           // w2t: 32x32 B-frags
    // block = (hq, kf): k-rows [hq*512+kf*16,+16), all 128 n-cols
    int bid3 = bid - 1152;
    int hq = bid3 >> 5, kf = bid3 & 31;
    _Float16* Ws = Xs;                               // reuse, [16][W2ROW]
    const float4* w2f4 = reinterpret_cast<const float4*>(w2);
    #pragma unroll
    for (int q = 0; q < 2; ++q){
      int idx = q*256 + t;                           // 512 float4s
      int row = idx >> 5, col4 = idx & 31;
      float4 v = w2f4[(size_t)(hq*512 + kf*16 + row)*32 + col4];
      half4 h;
      h[0]=(_Float16)v.x; h[1]=(_Float16)v.y; h[2]=(_Float16)v.z; h[3]=(_Float16)v.w;
      *reinterpret_cast<half4*>(Ws + row*W2ROW + col4*4) = h;
    }
    __syncthreads();
    // phase 2: 256 frag-lanes, 1 per thread
    int lane = t & 63, rt = t >> 6;
    int r0 = (lane >> 5)*8, c = rt*32 + (lane & 31);
    half8 v;
    #pragma unroll
    for (int j = 0; j < 8; ++j) v[j] = Ws[(r0 + j)*W2ROW + c];
    *reinterpret_cast<half8*>(
        w2t + (((size_t)(hq*32 + kf)*4 + rt)*512 + (size_t)lane*8)) = v;
  }
}

__global__ void k_init_out(const float* __restrict__ b2, float* __restrict__ out){
  int i = blockIdx.x*256 + threadIdx.x;              // 1048576 float4s
  float4 bv = reinterpret_cast<const float4*>(b2)[i & 31];
  reinterpret_cast<float4*>(out)[i] = bv;
}

// ---- reduce: out = b2 + sum over 8 H-eighth fp16 partials (R10 VERBATIM) ----
// partial u32 layout: [hq][tt][j][tc 32][r 128]; u32 = {tok t, tok t+8} halves
// where t = (tc>>3)*16 + (tc&7).
__global__ void k_reduce(const unsigned* __restrict__ part, const float* __restrict__ b2,
                         float* __restrict__ out){
  int tid = blockIdx.x*256 + threadIdx.x;            // 0..2097151
  int r   = tid & 127;
  int tc  = (tid >> 7) & 31;
  int j   = (tid >> 12) & 7;
  int tt  = tid >> 15;
  float s0 = 0.f, s1 = 0.f;
  #pragma unroll
  for (int hq = 0; hq < 8; ++hq){
    unsigned v = __builtin_nontemporal_load(part + (size_t)hq*2097152 + tid);
    half2v h = __builtin_bit_cast(half2v, v);
    s0 += (float)h[0];
    s1 += (float)h[1];
  }
  int tka = tt*64 + (tc >> 3)*16 + (tc & 7);
  float bb = b2[r];
  out[(size_t)tka*1024 + j*128 + r]       = s0 + bb;
  out[(size_t)(tka+8)*1024 + j*128 + r]   = s1 + bb;
}

// ---- main fused kernel (R10 VERBATIM) ----
// grid 512 x 768 thr (12 waves, 1 block/CU, 3 waves/EU -> 168-reg budget).
// block = (64 tok) x (H-8th 512).
__global__ __launch_bounds__(768, 3) void k_treemlp(
    const _Float16* __restrict__ xt, const _Float16* __restrict__ w1t,
    const _Float16* __restrict__ w2t, const float* __restrict__ b1,
    unsigned* __restrict__ partial, float* __restrict__ out, int use_partial){
  int b    = blockIdx.x;
  int hq   = b & 7;                     // H-eighth == XCD slot
  int tt   = b >> 3;                    // token tile 0..63 (64 tokens)
  int t    = threadIdx.x;
  int w    = t >> 6;                    // wave 0..11
  int lane = t & 63;
  int t32 = lane & 31, q2 = lane >> 5;

  __shared__ _Float16 Pbuf[2][32768];   // 2 x 64 KB: [th 2][kf 32][lane][8]
  __shared__ _Float16 Xls[2][8192];     // 2 x 16 KB: [tg 2][s 8][lane][8]

  // producer state: suffix accumulators (C^T: rows=hcol, cols=tok), b1-init
  f32x16 acc1[2][2];                    // [hcol-tile hf][tok-group tg]
  if (w < 8){
    #pragma unroll
    for (int hf = 0; hf < 2; ++hf){
      int base = hq*512 + (w*2 + hf)*32;
      #pragma unroll
      for (int g = 0; g < 4; ++g){
        float4 bv = *reinterpret_cast<const float4*>(b1 + base + 8*g + 4*q2);
        #pragma unroll
        for (int c = 0; c < 4; ++c){
          acc1[hf][0][g*4 + c] = ((const float*)&bv)[c];
          acc1[hf][1][g*4 + c] = ((const float*)&bv)[c];
        }
      }
    }
    // initial stage: level 7 -> Xls[1] (producers: 2 b128 each)
    #pragma unroll
    for (int c = 0; c < 2; ++c){
      int idx = c*512 + (w*64 + lane);
      int lane_s = idx & 63, s = (idx >> 6) & 7, tgl = idx >> 9;
      half8 v = *reinterpret_cast<const half8*>(
          xt + (size_t)((tt*2 + tgl)*64 + 7*8 + s)*512 + lane_s*8);
      *reinterpret_cast<half8*>(&Xls[1][(size_t)idx*8]) = v;
    }
  }
  __syncthreads();

  const _Float16* w1base = w1t + (size_t)hq*524288 + (size_t)(w*2)*512 + lane*8;
  int rt = w - 8;                       // consumer cell (R-tile of 32)
  const _Float16* w2base = w2t + ((size_t)(hq*32)*4 + rt)*512 + lane*8; // + kf*2048

  #pragma unroll
  for (int k = 0; k < 9; ++k){
    if (w < 8){
      // ================= PRODUCER =================
      if (k <= 7){
        int L = 7 - k;                   // level being produced
        // stage x(L-1) for next interval (2 b128 per producer thread)
        if (L >= 1){
          #pragma unroll
          for (int c = 0; c < 2; ++c){
            int idx = c*512 + (w*64 + lane);
            int lane_s = idx & 63, s = (idx >> 6) & 7, tgl = idx >> 9;
            half8 v = *reinterpret_cast<const half8*>(
                xt + (size_t)((tt*2 + tgl)*64 + (L-1)*8 + s)*512 + lane_s*8);
            *reinterpret_cast<half8*>(&Xls[(L-1) & 1][(size_t)idx*8]) = v;
          }
        }
        // GEMM1 level L: 2 chunks of 4 k-steps, 8 w1 frags batched in flight
        const _Float16* xb = Xls[L & 1];
        #pragma unroll
        for (int c2 = 0; c2 < 2; ++c2){
          half8 af[8];
          #pragma unroll
          for (int u = 0; u < 4; ++u){
            int kfg = L*8 + c2*4 + u;
            af[u*2    ] = *reinterpret_cast<const half8*>(w1base + (size_t)(kfg*16    )*512);
            af[u*2 + 1] = *reinterpret_cast<const half8*>(w1base + (size_t)(kfg*16 + 1)*512);
          }
          #pragma unroll
          for (int u = 0; u < 4; ++u){
            int s = c2*4 + u;
            half8 x0 = *reinterpret_cast<const half8*>(&xb[(size_t)((    s)*64 + lane)*8]);
            half8 x1 = *reinterpret_cast<const half8*>(&xb[(size_t)((8 + s)*64 + lane)*8]);
            acc1[0][0] = MFMA3216(af[u*2    ], x0, acc1[0][0]);
            acc1[0][1] = MFMA3216(af[u*2    ], x1, acc1[0][1]);
            acc1[1][0] = MFMA3216(af[u*2 + 1], x0, acc1[1][0]);
            acc1[1][1] = MFMA3216(af[u*2 + 1], x1, acc1[1][1]);
          }
        }
        // gelu (pkrtz pack) -> Pbuf[L&1] in 32x32 A-frag order
        _Float16* pb = Pbuf[L & 1];
        #pragma unroll
        for (int hf = 0; hf < 2; ++hf)
          #pragma unroll
          for (int tg = 0; tg < 2; ++tg)
            #pragma unroll
            for (int g2 = 0; g2 < 4; ++g2){
              fp16x2 lo = __builtin_amdgcn_cvt_pkrtz(
                  gelu_f(acc1[hf][tg][g2*4 + 0]), gelu_f(acc1[hf][tg][g2*4 + 1]));
              fp16x2 hi = __builtin_amdgcn_cvt_pkrtz(
                  gelu_f(acc1[hf][tg][g2*4 + 2]), gelu_f(acc1[hf][tg][g2*4 + 3]));
              half4 hv;
              hv[0]=(_Float16)lo[0]; hv[1]=(_Float16)lo[1];
              hv[2]=(_Float16)hi[0]; hv[3]=(_Float16)hi[1];
              int kf = (w*2 + hf)*2 + (g2 >> 1);
              *reinterpret_cast<half4*>(
                  &pb[(size_t)((tg*32 + kf)*64 + t32 + 32*(g2 & 1))*8 + 4*q2]) = hv;
            }
      }
    } else {
      // ================= CONSUMER =================
      if (k >= 1){
        int Lc = 8 - k;                  // level being consumed
        const _Float16* pb = Pbuf[Lc & 1];
        f32x16 o0, o1;
        #pragma unroll
        for (int c = 0; c < 16; ++c){ o0[c] = 0.f; o1[c] = 0.f; }
        #pragma unroll
        for (int c4 = 0; c4 < 4; ++c4){
          half8 wfb[8];
          #pragma unroll
          for (int u = 0; u < 8; ++u)
            wfb[u] = *reinterpret_cast<const half8*>(w2base + (size_t)(c4*8 + u)*2048);
          #pragma unroll
          for (int u = 0; u < 8; ++u){
            int kf = c4*8 + u;
            half8 p0 = *reinterpret_cast<const half8*>(&pb[(size_t)((     kf)*64 + lane)*8]);
            half8 p1 = *reinterpret_cast<const half8*>(&pb[(size_t)((32 + kf)*64 + lane)*8]);
            o0 = MFMA3216(p0, wfb[u], o0);
            o1 = MFMA3216(p1, wfb[u], o1);
          }
        }
        if (use_partial){
          // full-line stores: u32[hq][tt][j][tc][r]
          unsigned* pbase = partial + (size_t)hq*2097152 + (size_t)tt*32768
                          + (size_t)Lc*4096;
          #pragma unroll
          for (int th = 0; th < 2; ++th){
            const f32x16& oJ = th ? o1 : o0;
            #pragma unroll
            for (int i = 0; i < 8; ++i){
              int gg = i >> 2, ii = i & 3;
              int lo = gg*8 + ii;
              fp16x2 p = __builtin_amdgcn_cvt_pkrtz(oJ[lo], oJ[lo + 4]);
              int tc = (th*2 + gg)*8 + ii + 4*q2;
              __builtin_nontemporal_store(__builtin_bit_cast(unsigned, p),
                                          pbase + (size_t)tc*128 + rt*32 + t32);
            }
          }
        } else {
          #pragma unroll
          for (int th = 0; th < 2; ++th){
            const f32x16& oJ = th ? o1 : o0;
            #pragma unroll
            for (int reg = 0; reg < 16; ++reg){
              int tok = tt*64 + th*32 + (reg & 3) + 8*(reg >> 2) + 4*q2;
              atomicAdd(out + (size_t)tok*1024 + Lc*128 + rt*32 + t32, oJ[reg]);
            }
          }
        }
      }
    }
    __syncthreads();
  }
}

extern "C" void kernel_launch(void* const* d_in, const int* in_sizes, int n_in,
                              void* d_out, int out_size, void* d_ws, size_t ws_size,
                              hipStream_t stream){
  (void)in_sizes; (void)n_in; (void)out_size;
  const float* x  = (const float*)d_in[0];
  const float* W1 = (const float*)d_in[1];
  const float* b1 = (const float*)d_in[2];
  const float* W2 = (const float*)d_in[3];
  const float* b2 = (const float*)d_in[4];
  float* out = (float*)d_out;

  _Float16* xt  = (_Float16*)d_ws;
  _Float16* w1t = xt  + 4194304;
  _Float16* w2t = w1t + 4194304;
  unsigned* partial = (unsigned*)(w2t + 524288);   // 64 MB packed fp16
  const size_t need = (size_t)(4194304 + 4194304 + 524288)*2 + (size_t)16777216*4;
  int use_partial = (ws_size >= need) ? 1 : 0;

  hipLaunchKernelGGL(k_prep, dim3(1408), dim3(256), 0, stream, x, W1, W2, xt, w1t, w2t);
  if (!use_partial)
    hipLaunchKernelGGL(k_init_out, dim3(4096), dim3(256), 0, stream, b2, out);
  hipLaunchKernelGGL(k_treemlp, dim3(512), dim3(768), 0, stream,
                     xt, w1t, w2t, b1, partial, out, use_partial);
  if (use_partial)
    hipLaunchKernelGGL(k_reduce, dim3(8192), dim3(256), 0, stream, partial, b2, out);
}